// Round 8
// baseline (222.782 us; speedup 1.0000x reference)
//
#include <hip/hip_runtime.h>
#include <math.h>

#define TPB 256

typedef unsigned short u16;
typedef __attribute__((ext_vector_type(8))) short bf16x8;
typedef __attribute__((ext_vector_type(4))) float f32x4;

// ---------------- ws layout ----------------
// hB  : u16[524288]   @ u16 0        (1 MB)   h as RNE bf16 [b][n][64]
// blob: u16[106496]   @ u16 524288   (208 KB) fragment-linear A images
// baseRc : f32[1048576] @ f32 327680   (4 MB)  [b*64+i][128]
// baseAn : f32[524288]  @ f32 1376256  (2 MB)  [b*64+i][64]
// rc1_pre: f32[1048576] @ f32 1900544  (4 MB)  fragment order
// an1_pre: f32[524288]  @ f32 2949120  (2 MB)  fragment order
#define BLOB_U16 524288
#define BASE_RC_F32 327680
#define BASE_AN_F32 1376256
#define RC1P_F32 1900544
#define AN1P_F32 2949120
#define WS_NEED_BASES ((size_t)1900544 * 4)  // ~7.6 MB
#define WS_NEED_PRE   ((size_t)3473408 * 4)  // ~13.9 MB
// blob-internal u16 offsets (hi[OK] then lo[OK]; lo unused for hi-only layers)
#define RC1F 0       // O=128, K=64  (rc_w1 rows 64..127) T=8 OK=8192  [2-term, fallback only]
#define AN1F 16384   // O=64,  K=64  (an_w1 rows 64..127) T=4 OK=4096  [2-term, fallback only]
#define AN2F 24576   // O=128, K=64  T=8 OK=8192  [hi-only RNE]
#define RC2F 40960   // O=128, K=128 T=8 OK=16384 [hi-only RNE]
#define RC3F 73728   // O=128, K=128 T=8 OK=16384 [hi-only RNE]

__device__ __forceinline__ float b2f(u16 h) {
  return __uint_as_float(((unsigned)h) << 16);
}
__device__ __forceinline__ void split_bf16(float x, u16& hi, u16& lo) {
  unsigned u = __float_as_uint(x);
  hi = (u16)(u >> 16);
  float hif = __uint_as_float(u & 0xFFFF0000u);
  lo = (u16)(__float_as_uint(x - hif) >> 16);
}
__device__ __forceinline__ u16 f2bf_rne(float x) {
  unsigned u = __float_as_uint(x);
  return (u16)((u + 0x7FFFu + ((u >> 16) & 1u)) >> 16);
}
// fast pack: two f32 -> bf16x2 via round-half-up + byte-perm
__device__ __forceinline__ unsigned pack_bf16_hu(float v0, float v1) {
  unsigned a = __float_as_uint(v0) + 0x8000u;
  unsigned b = __float_as_uint(v1) + 0x8000u;
  return __builtin_amdgcn_perm(b, a, 0x07060302u);
}

__device__ __forceinline__ void cp_lds(float* dst, const float* src, int nfloats, int tid) {
  const float4* s4 = (const float4*)src;
  float4* d4 = (float4*)dst;
  const int n4 = nfloats >> 2;
  for (int i = tid; i < n4; i += TPB) d4[i] = s4[i];
}
__device__ __forceinline__ void ld4(float r[4], const float* p) {
  float4 v = *(const float4*)p;
  r[0] = v.x; r[1] = v.y; r[2] = v.z; r[3] = v.w;
}
__device__ __forceinline__ void ld2(float r[2], const float* p) {
  float2 v = *(const float2*)p;
  r[0] = v.x; r[1] = v.y;
}

// ---------------------------------------------------------------------------
// Kernel A (fused): blocks 0..255 = encoder: h -> hB, self_dyn -> out (atomic),
// bases (do_bases) and f32 L1 h_j-pre GEMMs in fragment order (do_pre).
// Blocks 256..463 = weight prep into blob.
// ---------------------------------------------------------------------------
__global__ __launch_bounds__(TPB, 3) void enc_prep_kernel(
    const float* __restrict__ s_in,
    const float* __restrict__ se_w1, const float* __restrict__ se_b1,
    const float* __restrict__ se_w2, const float* __restrict__ se_b2,
    const float* __restrict__ sd_w1, const float* __restrict__ sd_b1,
    const float* __restrict__ sd_w2, const float* __restrict__ sd_b2,
    const float* __restrict__ rc_w1, const float* __restrict__ rc_b1,
    const float* __restrict__ rc_w2, const float* __restrict__ rc_w3,
    const float* __restrict__ an_w1, const float* __restrict__ an_b1,
    const float* __restrict__ an_w2,
    u16* __restrict__ hB, u16* __restrict__ blob,
    float* __restrict__ baseRcG, float* __restrict__ baseAnG,
    float* __restrict__ rc1pG, float* __restrict__ an1pG,
    int do_bases, int do_pre,
    float* __restrict__ out) {
  if (blockIdx.x >= 256) {
    int idx = (int)(blockIdx.x - 256) * TPB + threadIdx.x;
    if (idx >= 53248) return;
    int r, base, OK, T; const float* W; int Wld, krow0, twoTerm;
    if (idx < 8192)       { r = idx;         base = RC1F; OK = 8192;  T = 8; W = rc_w1; Wld = 128; krow0 = 64; twoTerm = 1; }
    else if (idx < 12288) { r = idx - 8192;  base = AN1F; OK = 4096;  T = 4; W = an_w1; Wld = 64;  krow0 = 64; twoTerm = 1; }
    else if (idx < 20480) { r = idx - 12288; base = AN2F; OK = 8192;  T = 8; W = an_w2; Wld = 128; krow0 = 0;  twoTerm = 0; }
    else if (idx < 36864) { r = idx - 20480; base = RC2F; OK = 16384; T = 8; W = rc_w2; Wld = 128; krow0 = 0;  twoTerm = 0; }
    else                  { r = idx - 36864; base = RC3F; OK = 16384; T = 8; W = rc_w3; Wld = 128; krow0 = 0;  twoTerm = 0; }
    const int u = r & 7;
    const int lane = (r >> 3) & 63;
    const int ct = r >> 9;
    const int c = (T == 8) ? (ct >> 3) : (ct >> 2);
    const int tg = (T == 8) ? (ct & 7) : (ct & 3);
    const int o = tg * 16 + (lane & 15);
    const int k = c * 32 + (lane >> 4) * 8 + u;
    const float x = W[(krow0 + k) * Wld + o];
    if (twoTerm) {
      u16 hi, lo; split_bf16(x, hi, lo);
      blob[base + r] = hi;
      blob[base + OK + r] = lo;
    } else {
      blob[base + r] = f2bf_rne(x);
    }
    return;
  }

  // ---- encoder role
  __shared__ __align__(16) float sX[2048];
  __shared__ __align__(16) float sH1[2048];
  __shared__ __align__(16) float sT[4096];
  __shared__ __align__(16) float sW[4096];
  __shared__ float sb1[64], sb2[64], sdb1[128], sdb2[128], srb1[128], sab1[64];

  const int tid = threadIdx.x;
  const int lg = tid >> 5;
  const int og = tid & 31;
  const int b = blockIdx.x >> 1;
  const int half = blockIdx.x & 1;
  const int row0 = b * 64 + half * 32;
  const int n0 = lg * 4;

  cp_lds(sX, s_in + row0 * 64, 2048, tid);
  cp_lds(sW, se_w1, 4096, tid);
  if (tid < 64) { sb1[tid] = se_b1[tid]; sb2[tid] = se_b2[tid]; }
  else if (tid < 192) { const int o = tid - 64; sdb1[o] = sd_b1[o]; sdb2[o] = sd_b2[o]; }
  if (tid < 128) srb1[tid] = rc_b1[tid];
  else if (tid < 192) sab1[tid - 128] = an_b1[tid - 128];
  __syncthreads();

  float a2[4][2];
#pragma unroll
  for (int nn = 0; nn < 4; nn++) { a2[nn][0] = 0.f; a2[nn][1] = 0.f; }
  for (int kk = 0; kk < 64; kk += 4) {
    float xr[4][4], wr[4][2];
#pragma unroll
    for (int nn = 0; nn < 4; nn++) ld4(xr[nn], &sX[(n0 + nn) * 64 + kk]);
#pragma unroll
    for (int t = 0; t < 4; t++) ld2(wr[t], &sW[(kk + t) * 64 + og * 2]);
#pragma unroll
    for (int t = 0; t < 4; t++)
#pragma unroll
      for (int nn = 0; nn < 4; nn++) {
        a2[nn][0] = fmaf(xr[nn][t], wr[t][0], a2[nn][0]);
        a2[nn][1] = fmaf(xr[nn][t], wr[t][1], a2[nn][1]);
      }
  }
#pragma unroll
  for (int nn = 0; nn < 4; nn++) {
    float2 v;
    v.x = fmaxf(a2[nn][0] + sb1[og * 2 + 0], 0.f);
    v.y = fmaxf(a2[nn][1] + sb1[og * 2 + 1], 0.f);
    *(float2*)&sH1[(n0 + nn) * 64 + og * 2] = v;
  }
  __syncthreads();
  cp_lds(sW, se_w2, 4096, tid);
  __syncthreads();

#pragma unroll
  for (int nn = 0; nn < 4; nn++) { a2[nn][0] = 0.f; a2[nn][1] = 0.f; }
  for (int kk = 0; kk < 64; kk += 4) {
    float xr[4][4], wr[4][2];
#pragma unroll
    for (int nn = 0; nn < 4; nn++) ld4(xr[nn], &sH1[(n0 + nn) * 64 + kk]);
#pragma unroll
    for (int t = 0; t < 4; t++) ld2(wr[t], &sW[(kk + t) * 64 + og * 2]);
#pragma unroll
    for (int t = 0; t < 4; t++)
#pragma unroll
      for (int nn = 0; nn < 4; nn++) {
        a2[nn][0] = fmaf(xr[nn][t], wr[t][0], a2[nn][0]);
        a2[nn][1] = fmaf(xr[nn][t], wr[t][1], a2[nn][1]);
      }
  }
#pragma unroll
  for (int nn = 0; nn < 4; nn++) {
    float2 v;
    v.x = fmaxf(a2[nn][0] + sb2[og * 2 + 0], 0.f);
    v.y = fmaxf(a2[nn][1] + sb2[og * 2 + 1], 0.f);
    *(float2*)&sX[(n0 + nn) * 64 + og * 2] = v;
    const int off = (row0 + n0 + nn) * 64 + og * 2;
    *(ushort2*)&hB[off] = make_ushort2(f2bf_rne(v.x), f2bf_rne(v.y));
  }
  __syncthreads();

  float a4[4][4];
#pragma unroll
  for (int nn = 0; nn < 4; nn++)
#pragma unroll
    for (int oo = 0; oo < 4; oo++) a4[nn][oo] = 0.f;
  for (int c = 0; c < 2; c++) {
    cp_lds(sW, sd_w1 + c * 32 * 128, 4096, tid);
    __syncthreads();
    for (int kk = 0; kk < 32; kk += 4) {
      float xr[4][4], wr[4][4];
#pragma unroll
      for (int nn = 0; nn < 4; nn++) ld4(xr[nn], &sX[(n0 + nn) * 64 + c * 32 + kk]);
#pragma unroll
      for (int t = 0; t < 4; t++) ld4(wr[t], &sW[(kk + t) * 128 + og * 4]);
#pragma unroll
      for (int t = 0; t < 4; t++)
#pragma unroll
        for (int nn = 0; nn < 4; nn++)
#pragma unroll
          for (int oo = 0; oo < 4; oo++)
            a4[nn][oo] = fmaf(xr[nn][t], wr[t][oo], a4[nn][oo]);
    }
    __syncthreads();
  }
#pragma unroll
  for (int nn = 0; nn < 4; nn++) {
    float4 v;
    v.x = fmaxf(a4[nn][0] + sdb1[og * 4 + 0], 0.f);
    v.y = fmaxf(a4[nn][1] + sdb1[og * 4 + 1], 0.f);
    v.z = fmaxf(a4[nn][2] + sdb1[og * 4 + 2], 0.f);
    v.w = fmaxf(a4[nn][3] + sdb1[og * 4 + 3], 0.f);
    *(float4*)&sT[(n0 + nn) * 128 + og * 4] = v;
  }
  __syncthreads();

#pragma unroll
  for (int nn = 0; nn < 4; nn++)
#pragma unroll
    for (int oo = 0; oo < 4; oo++) a4[nn][oo] = 0.f;
  for (int c = 0; c < 4; c++) {
    cp_lds(sW, sd_w2 + c * 32 * 128, 4096, tid);
    __syncthreads();
    for (int kk = 0; kk < 32; kk += 4) {
      float xr[4][4], wr[4][4];
#pragma unroll
      for (int nn = 0; nn < 4; nn++) ld4(xr[nn], &sT[(n0 + nn) * 128 + c * 32 + kk]);
#pragma unroll
      for (int t = 0; t < 4; t++) ld4(wr[t], &sW[(kk + t) * 128 + og * 4]);
#pragma unroll
      for (int t = 0; t < 4; t++)
#pragma unroll
        for (int nn = 0; nn < 4; nn++)
#pragma unroll
          for (int oo = 0; oo < 4; oo++)
            a4[nn][oo] = fmaf(xr[nn][t], wr[t][oo], a4[nn][oo]);
    }
    __syncthreads();
  }
  float p[4];
#pragma unroll
  for (int oo = 0; oo < 4; oo++)
    p[oo] = a4[0][oo] + a4[1][oo] + a4[2][oo] + a4[3][oo] + 4.f * sdb2[og * 4 + oo];
  *(float4*)&sH1[lg * 128 + og * 4] = make_float4(p[0], p[1], p[2], p[3]);
  __syncthreads();
  if (tid < 128) {
    float ssum = 0.f;
#pragma unroll
    for (int g = 0; g < 8; g++) ssum += sH1[g * 128 + tid];
    atomicAdd(&out[b * 128 + tid], ssum * (1.0f / 64.0f));
  }

  if (do_bases) {
    // ---- baseRc = rc_b1 + h @ rc_w1[0:64]
#pragma unroll
    for (int nn = 0; nn < 4; nn++)
#pragma unroll
      for (int oo = 0; oo < 4; oo++) a4[nn][oo] = 0.f;
    for (int c = 0; c < 2; c++) {
      __syncthreads();
      cp_lds(sW, rc_w1 + c * 32 * 128, 4096, tid);
      __syncthreads();
      for (int kk = 0; kk < 32; kk += 4) {
        float xr[4][4], wr[4][4];
#pragma unroll
        for (int nn = 0; nn < 4; nn++) ld4(xr[nn], &sX[(n0 + nn) * 64 + c * 32 + kk]);
#pragma unroll
        for (int t = 0; t < 4; t++) ld4(wr[t], &sW[(kk + t) * 128 + og * 4]);
#pragma unroll
        for (int t = 0; t < 4; t++)
#pragma unroll
          for (int nn = 0; nn < 4; nn++)
#pragma unroll
            for (int oo = 0; oo < 4; oo++)
              a4[nn][oo] = fmaf(xr[nn][t], wr[t][oo], a4[nn][oo]);
      }
    }
#pragma unroll
    for (int nn = 0; nn < 4; nn++) {
      float4 v;
      v.x = a4[nn][0] + srb1[og * 4 + 0];
      v.y = a4[nn][1] + srb1[og * 4 + 1];
      v.z = a4[nn][2] + srb1[og * 4 + 2];
      v.w = a4[nn][3] + srb1[og * 4 + 3];
      *(float4*)&baseRcG[(size_t)(row0 + n0 + nn) * 128 + og * 4] = v;
    }
    __syncthreads();
    cp_lds(sW, an_w1, 4096, tid);
    __syncthreads();
#pragma unroll
    for (int nn = 0; nn < 4; nn++) { a2[nn][0] = 0.f; a2[nn][1] = 0.f; }
    for (int kk = 0; kk < 64; kk += 4) {
      float xr[4][4], wr[4][2];
#pragma unroll
      for (int nn = 0; nn < 4; nn++) ld4(xr[nn], &sX[(n0 + nn) * 64 + kk]);
#pragma unroll
      for (int t = 0; t < 4; t++) ld2(wr[t], &sW[(kk + t) * 64 + og * 2]);
#pragma unroll
      for (int t = 0; t < 4; t++)
#pragma unroll
        for (int nn = 0; nn < 4; nn++) {
          a2[nn][0] = fmaf(xr[nn][t], wr[t][0], a2[nn][0]);
          a2[nn][1] = fmaf(xr[nn][t], wr[t][1], a2[nn][1]);
        }
    }
#pragma unroll
    for (int nn = 0; nn < 4; nn++) {
      float2 v;
      v.x = a2[nn][0] + sab1[og * 2 + 0];
      v.y = a2[nn][1] + sab1[og * 2 + 1];
      *(float2*)&baseAnG[(size_t)(row0 + n0 + nn) * 64 + og * 2] = v;
    }
  }

  if (do_pre) {
    // ---- rc1_pre = h @ rc_w1[64:128]  (f32, fragment order)
#pragma unroll
    for (int nn = 0; nn < 4; nn++)
#pragma unroll
      for (int oo = 0; oo < 4; oo++) a4[nn][oo] = 0.f;
    for (int c = 0; c < 2; c++) {
      __syncthreads();
      cp_lds(sW, rc_w1 + (64 + c * 32) * 128, 4096, tid);
      __syncthreads();
      for (int kk = 0; kk < 32; kk += 4) {
        float xr[4][4], wr[4][4];
#pragma unroll
        for (int nn = 0; nn < 4; nn++) ld4(xr[nn], &sX[(n0 + nn) * 64 + c * 32 + kk]);
#pragma unroll
        for (int t = 0; t < 4; t++) ld4(wr[t], &sW[(kk + t) * 128 + og * 4]);
#pragma unroll
        for (int t = 0; t < 4; t++)
#pragma unroll
          for (int nn = 0; nn < 4; nn++)
#pragma unroll
            for (int oo = 0; oo < 4; oo++)
              a4[nn][oo] = fmaf(xr[nn][t], wr[t][oo], a4[nn][oo]);
      }
    }
#pragma unroll
    for (int nn = 0; nn < 4; nn++) {
      const int jl = half * 32 + n0 + nn;
      const int addr = ((b * 8 + (og >> 2)) * 4 + (jl >> 4)) * 256 +
                       ((og & 3) * 16 + (jl & 15)) * 4;
      *(float4*)&rc1pG[addr] = make_float4(a4[nn][0], a4[nn][1], a4[nn][2], a4[nn][3]);
    }
    // ---- an1_pre = h @ an_w1[64:128]
    __syncthreads();
    cp_lds(sW, an_w1 + 64 * 64, 4096, tid);
    __syncthreads();
#pragma unroll
    for (int nn = 0; nn < 4; nn++) { a2[nn][0] = 0.f; a2[nn][1] = 0.f; }
    for (int kk = 0; kk < 64; kk += 4) {
      float xr[4][4], wr[4][2];
#pragma unroll
      for (int nn = 0; nn < 4; nn++) ld4(xr[nn], &sX[(n0 + nn) * 64 + kk]);
#pragma unroll
      for (int t = 0; t < 4; t++) ld2(wr[t], &sW[(kk + t) * 64 + og * 2]);
#pragma unroll
      for (int t = 0; t < 4; t++)
#pragma unroll
        for (int nn = 0; nn < 4; nn++) {
          a2[nn][0] = fmaf(xr[nn][t], wr[t][0], a2[nn][0]);
          a2[nn][1] = fmaf(xr[nn][t], wr[t][1], a2[nn][1]);
        }
    }
#pragma unroll
    for (int nn = 0; nn < 4; nn++) {
      const int jl = half * 32 + n0 + nn;
      const int addr = ((b * 4 + (og >> 3)) * 4 + (jl >> 4)) * 256 +
                       (((og >> 1) & 3) * 16 + (jl & 15)) * 4 + (og & 1) * 2;
      *(float2*)&an1pG[addr] = make_float2(a2[nn][0], a2[nn][1]);
    }
  }
}

// ---------------------------------------------------------------------------
// MFMA layer helpers (A from global blob; B from XOR-swizzled LDS).
// ---------------------------------------------------------------------------
template<int MT, int NCHUNK, int RSG, int TILES>
__device__ __forceinline__ void run_layer1(f32x4 (&acc)[MT][4],
    const u16* __restrict__ blobL,
    const u16* __restrict__ sB, int tg0, int quad, int l15) {
  const int lane = quad * 16 + l15;
#pragma unroll
  for (int c = 0; c < NCHUNK; ++c) {
    bf16x8 Ah[MT];
#pragma unroll
    for (int t = 0; t < MT; ++t)
      Ah[t] = *(const bf16x8*)(blobL + ((c * TILES + tg0 + t) * 64 + lane) * 8);
    const int slot = (4 * c + quad) ^ (l15 & 7);
    bf16x8 Bh[4];
#pragma unroll
    for (int s = 0; s < 4; ++s)
      Bh[s] = *(const bf16x8*)&sB[(16 * s + l15) * (RSG * 8) + slot * 8];
#pragma unroll
    for (int t = 0; t < MT; ++t)
#pragma unroll
      for (int s = 0; s < 4; ++s)
        acc[t][s] = __builtin_amdgcn_mfma_f32_16x16x32_bf16(Ah[t], Bh[s], acc[t][s], 0, 0, 0);
  }
}

// relu -> half-up bf16 pack -> swizzled LDS store. Bias already in acc.
template<int MT, int RSG>
__device__ __forceinline__ void store_acts_pk(const f32x4 (&acc)[MT][4],
                                              u16* dst, int o0, int quad, int l15) {
#pragma unroll
  for (int t = 0; t < MT; ++t) {
    const int ob = o0 + 16 * t + quad * 4;
    const int slot = (ob >> 3) ^ (l15 & 7);
    const int e = ob & 7;
#pragma unroll
    for (int s = 0; s < 4; ++s) {
      const int j = 16 * s + l15;
      uint2 pk;
      pk.x = pack_bf16_hu(fmaxf(acc[t][s][0], 0.f), fmaxf(acc[t][s][1], 0.f));
      pk.y = pack_bf16_hu(fmaxf(acc[t][s][2], 0.f), fmaxf(acc[t][s][3], 0.f));
      *(uint2*)&dst[j * (RSG * 8) + slot * 8 + e] = pk;
    }
  }
}

// ---------------------------------------------------------------------------
// Kernel B (MFMA): one block per (b,i). ~28 KB LDS -> 5 blocks/CU.
// Fast path (has_pre): L1 = coalesced pre-frag loads + epilogue (no L1 MFMA,
// no h_j staging). 80 MFMA/wave. Fallback = R7 path.
// ---------------------------------------------------------------------------
__global__ __launch_bounds__(TPB, 5) void pair_mfma_kernel(
    const u16* __restrict__ hB, const u16* __restrict__ blob,
    const float* __restrict__ baseRcG, const float* __restrict__ baseAnG,
    const float* __restrict__ rc1pG, const float* __restrict__ an1pG,
    int has_bases, int has_pre,
    const float* __restrict__ rc_w1, const float* __restrict__ rc_b1,
    const float* __restrict__ rc_b2, const float* __restrict__ rc_b3,
    const float* __restrict__ an_w1, const float* __restrict__ an_b1,
    const float* __restrict__ an_b2,
    float* __restrict__ out) {
  __shared__ __align__(16) u16 sAct[64 * 128];  // 16 KB
  __shared__ __align__(16) u16 sAn[64 * 64];    // 8 KB
  __shared__ float sHi[64], sDist[64];
  __shared__ float sBaseRc[128], sBaseAn[64], sW1d[128], sAnd[64];
  __shared__ float sB2[128], sB3[128], sAb2[128], sRed[128];

  const int tid = threadIdx.x;
  const int w = tid >> 6, lane = tid & 63;
  const int quad = lane >> 4, l15 = lane & 15;
  const int b = blockIdx.x >> 6, i = blockIdx.x & 63;
  const int o0 = w * 32;
  const int o0a = w * 16;

  f32x4 accR[2][4];
  f32x4 accN[1][4];

  if (has_pre) {
    // ======== fast path: no h_j staging, no L1 MFMA ========
    if (tid < 128) {
      sW1d[tid] = rc_w1[128 * 128 + tid];
      sB2[tid] = rc_b2[tid]; sB3[tid] = rc_b3[tid]; sAb2[tid] = an_b2[tid];
    } else if (tid < 192) {
      sAnd[tid - 128] = an_w1[128 * 64 + (tid - 128)];
    } else {
      const int j = tid - 192;
      const float hi0 = b2f(hB[(b * 64 + i) * 64 + 0]);
      const float hi1 = b2f(hB[(b * 64 + i) * 64 + 1]);
      const ushort2 hj = *(const ushort2*)&hB[(b * 64 + j) * 64];
      const float d0 = hi0 - b2f(hj.x), d1 = hi1 - b2f(hj.y);
      sDist[j] = d0 * d0 + d1 * d1;
    }
    if (tid < 32)
      ((float4*)sBaseRc)[tid] = ((const float4*)(baseRcG + (size_t)(b * 64 + i) * 128))[tid];
    else if (tid < 48)
      ((float4*)sBaseAn)[tid - 32] = ((const float4*)(baseAnG + (size_t)(b * 64 + i) * 64))[tid - 32];
    __syncthreads();

    float bbR[2][4], wwR[2][4], bbN[4], wwN[4];
#pragma unroll
    for (int t = 0; t < 2; ++t) {
      ld4(bbR[t], &sBaseRc[o0 + 16 * t + quad * 4]);
      ld4(wwR[t], &sW1d[o0 + 16 * t + quad * 4]);
    }
    ld4(bbN, &sBaseAn[o0a + quad * 4]);
    ld4(wwN, &sAnd[o0a + quad * 4]);
    const float* pR = rc1pG + (size_t)(b * 8 + 2 * w) * 1024 + lane * 4;
    const float* pA = an1pG + (size_t)(b * 4 + w) * 1024 + lane * 4;
#pragma unroll
    for (int s = 0; s < 4; ++s) {
      const float dj = sDist[16 * s + l15];
#pragma unroll
      for (int t = 0; t < 2; ++t) {
        const float4 pre = *(const float4*)(pR + t * 1024 + s * 256);
        f32x4 a;
        a[0] = pre.x + fmaf(dj, wwR[t][0], bbR[t][0]);
        a[1] = pre.y + fmaf(dj, wwR[t][1], bbR[t][1]);
        a[2] = pre.z + fmaf(dj, wwR[t][2], bbR[t][2]);
        a[3] = pre.w + fmaf(dj, wwR[t][3], bbR[t][3]);
        accR[t][s] = a;
      }
      const float4 pre = *(const float4*)(pA + s * 256);
      f32x4 a;
      a[0] = pre.x + fmaf(dj, wwN[0], bbN[0]);
      a[1] = pre.y + fmaf(dj, wwN[1], bbN[1]);
      a[2] = pre.z + fmaf(dj, wwN[2], bbN[2]);
      a[3] = pre.w + fmaf(dj, wwN[3], bbN[3]);
      accN[0][s] = a;
    }
    store_acts_pk<1, 8>(accN, sAn, o0a, quad, l15);
    store_acts_pk<2, 16>(accR, sAct, o0, quad, l15);
    __syncthreads();
  } else {
    // ======== fallback: R7 path (L1 via MFMA, in-block/global bases) ========
    {
      const float4* srcJ = (const float4*)(hB + b * 4096);
      for (int idx = tid; idx < 512; idx += TPB) {
        const int row = idx >> 3, g = idx & 7;
        *(float4*)&sAct[row * 128 + ((g ^ (row & 7)) * 8)] = srcJ[idx];
      }
    }
    if (has_bases) {
      const float4* bR = (const float4*)(baseRcG + (size_t)(b * 64 + i) * 128);
      const float4* bA = (const float4*)(baseAnG + (size_t)(b * 64 + i) * 64);
      if (tid < 32) ((float4*)sBaseRc)[tid] = bR[tid];
      else if (tid < 48) ((float4*)sBaseAn)[tid - 32] = bA[tid - 32];
    }
    if (tid < 64) sHi[tid] = b2f(hB[(b * 64 + i) * 64 + tid]);
    if (tid < 128) {
      sW1d[tid] = rc_w1[128 * 128 + tid];
      sB2[tid] = rc_b2[tid]; sB3[tid] = rc_b3[tid]; sAb2[tid] = an_b2[tid];
    } else if (tid < 192) {
      sAnd[tid - 128] = an_w1[128 * 64 + (tid - 128)];
    }
    __syncthreads();
    if (!has_bases) {
      if (tid < 128) {
        float acc = rc_b1[tid];
        for (int k = 0; k < 64; ++k) acc = fmaf(sHi[k], rc_w1[k * 128 + tid], acc);
        sBaseRc[tid] = acc;
      } else if (tid < 192) {
        const int o = tid - 128;
        float acc = an_b1[o];
        for (int k = 0; k < 64; ++k) acc = fmaf(sHi[k], an_w1[k * 64 + o], acc);
        sBaseAn[o] = acc;
      }
    }
    if (tid >= 192) {
      const int j = tid - 192;
      const int base = j * 128 + ((0 ^ (j & 7)) * 8);
      const float d0 = sHi[0] - b2f(sAct[base + 0]);
      const float d1 = sHi[1] - b2f(sAct[base + 1]);
      sDist[j] = d0 * d0 + d1 * d1;
    }
    __syncthreads();

    {
      float bbR[2][4], wwR[2][4], bbN[4], wwN[4];
#pragma unroll
      for (int t = 0; t < 2; ++t) {
        ld4(bbR[t], &sBaseRc[o0 + 16 * t + quad * 4]);
        ld4(wwR[t], &sW1d[o0 + 16 * t + quad * 4]);
      }
      ld4(bbN, &sBaseAn[o0a + quad * 4]);
      ld4(wwN, &sAnd[o0a + quad * 4]);
#pragma unroll
      for (int s = 0; s < 4; ++s) {
        const float dj = sDist[16 * s + l15];
#pragma unroll
        for (int t = 0; t < 2; ++t) {
          f32x4 a;
#pragma unroll
          for (int r = 0; r < 4; ++r) a[r] = fmaf(dj, wwR[t][r], bbR[t][r]);
          accR[t][s] = a;
        }
        f32x4 a;
#pragma unroll
        for (int r = 0; r < 4; ++r) a[r] = fmaf(dj, wwN[r], bbN[r]);
        accN[0][s] = a;
      }
    }
    {
      const int lane64 = quad * 16 + l15;
#pragma unroll
      for (int c = 0; c < 2; ++c) {
        bf16x8 Ah[2], Al[2], AhN, AlN;
#pragma unroll
        for (int t = 0; t < 2; ++t) {
          const u16* p = blob + RC1F + ((c * 8 + 2 * w + t) * 64 + lane64) * 8;
          Ah[t] = *(const bf16x8*)p;
          Al[t] = *(const bf16x8*)(p + 8192);
        }
        {
          const u16* p = blob + AN1F + ((c * 4 + w) * 64 + lane64) * 8;
          AhN = *(const bf16x8*)p;
          AlN = *(const bf16x8*)(p + 4096);
        }
        const int slot = (4 * c + quad) ^ (l15 & 7);
        bf16x8 Bh[4];
#pragma unroll
        for (int s = 0; s < 4; ++s)
          Bh[s] = *(const bf16x8*)&sAct[(16 * s + l15) * 128 + slot * 8];
#pragma unroll
        for (int s = 0; s < 4; ++s) {
#pragma unroll
          for (int t = 0; t < 2; ++t) {
            f32x4 a = accR[t][s];
            a = __builtin_amdgcn_mfma_f32_16x16x32_bf16(Ah[t], Bh[s], a, 0, 0, 0);
            a = __builtin_amdgcn_mfma_f32_16x16x32_bf16(Al[t], Bh[s], a, 0, 0, 0);
            accR[t][s] = a;
          }
          f32x4 a = accN[0][s];
          a = __builtin_amdgcn_mfma_f32_16x16x32_bf16(AhN, Bh[s], a, 0, 0, 0);
          a = __builtin_amdgcn_mfma_f32_16x16x32_bf16(AlN, Bh[s], a, 0, 0, 0);
          accN[0][s] = a;
        }
      }
    }
    store_acts_pk<1, 8>(accN, sAn, o0a, quad, l15);
    __syncthreads();
    store_acts_pk<2, 16>(accR, sAct, o0, quad, l15);
    __syncthreads();
  }

  // ======== common tail: an2 -> att, rc2, rc3 + reduce ========
  f32x4 accT[2][4];
  {
    float bb[2][4];
#pragma unroll
    for (int t = 0; t < 2; ++t) ld4(bb[t], &sAb2[o0 + 16 * t + quad * 4]);
#pragma unroll
    for (int t = 0; t < 2; ++t)
#pragma unroll
      for (int s = 0; s < 4; ++s) {
        f32x4 a;
#pragma unroll
        for (int r = 0; r < 4; ++r) a[r] = bb[t][r];
        accT[t][s] = a;
      }
  }
  run_layer1<2, 2, 8, 8>(accT, blob + AN2F, sAn, 2 * w, quad, l15);
  float att[2][4][4];
#pragma unroll
  for (int t = 0; t < 2; ++t)
#pragma unroll
    for (int s = 0; s < 4; ++s)
#pragma unroll
      for (int r = 0; r < 4; ++r)
        att[t][s][r] = 1.0f / (1.0f + __expf(-accT[t][s][r]));

  {
    float bb[2][4];
#pragma unroll
    for (int t = 0; t < 2; ++t) ld4(bb[t], &sB2[o0 + 16 * t + quad * 4]);
#pragma unroll
    for (int t = 0; t < 2; ++t)
#pragma unroll
      for (int s = 0; s < 4; ++s) {
        f32x4 a;
#pragma unroll
        for (int r = 0; r < 4; ++r) a[r] = bb[t][r];
        accR[t][s] = a;
      }
  }
  run_layer1<2, 4, 16, 8>(accR, blob + RC2F, sAct, 2 * w, quad, l15);
  __syncthreads();
  store_acts_pk<2, 16>(accR, sAct, o0, quad, l15);
  __syncthreads();

  {
    float bb[2][4];
#pragma unroll
    for (int t = 0; t < 2; ++t) ld4(bb[t], &sB3[o0 + 16 * t + quad * 4]);
#pragma unroll
    for (int t = 0; t < 2; ++t)
#pragma unroll
      for (int s = 0; s < 4; ++s) {
        f32x4 a;
#pragma unroll
        for (int r = 0; r < 4; ++r) a[r] = bb[t][r];
        accR[t][s] = a;
      }
  }
  run_layer1<2, 4, 16, 8>(accR, blob + RC3F, sAct, 2 * w, quad, l15);
  float ps[2][4] = {{0.f, 0.f, 0.f, 0.f}, {0.f, 0.f, 0.f, 0.f}};
#pragma unroll
  for (int t = 0; t < 2; ++t)
#pragma unroll
    for (int s = 0; s < 4; ++s)
#pragma unroll
      for (int r = 0; r < 4; ++r) {
        const float rel = fmaxf(accR[t][s][r], 0.f);
        ps[t][r] = fmaf(rel, att[t][s][r], ps[t][r]);
      }
#pragma unroll
  for (int t = 0; t < 2; ++t)
#pragma unroll
    for (int r = 0; r < 4; ++r) {
      float v = ps[t][r];
      v += __shfl_xor(v, 1, 64);
      v += __shfl_xor(v, 2, 64);
      v += __shfl_xor(v, 4, 64);
      v += __shfl_xor(v, 8, 64);
      ps[t][r] = v;
    }
  if (l15 == 0) {
#pragma unroll
    for (int t = 0; t < 2; ++t)
#pragma unroll
      for (int r = 0; r < 4; ++r)
        sRed[o0 + 16 * t + quad * 4 + r] = ps[t][r];
  }
  __syncthreads();
  if (tid < 128)
    atomicAdd(&out[b * 128 + tid], sRed[tid] * (1.0f / 4096.0f));
}

extern "C" void kernel_launch(void* const* d_in, const int* in_sizes, int n_in,
                              void* d_out, int out_size, void* d_ws, size_t ws_size,
                              hipStream_t stream) {
  const float* s     = (const float*)d_in[0];
  const float* se_w1 = (const float*)d_in[1];
  const float* se_b1 = (const float*)d_in[2];
  const float* se_w2 = (const float*)d_in[3];
  const float* se_b2 = (const float*)d_in[4];
  const float* sd_w1 = (const float*)d_in[5];
  const float* sd_b1 = (const float*)d_in[6];
  const float* sd_w2 = (const float*)d_in[7];
  const float* sd_b2 = (const float*)d_in[8];
  const float* rc_w1 = (const float*)d_in[9];
  const float* rc_b1 = (const float*)d_in[10];
  const float* rc_w2 = (const float*)d_in[11];
  const float* rc_b2 = (const float*)d_in[12];
  const float* rc_w3 = (const float*)d_in[13];
  const float* rc_b3 = (const float*)d_in[14];
  const float* an_w1 = (const float*)d_in[15];
  const float* an_b1 = (const float*)d_in[16];
  const float* an_w2 = (const float*)d_in[17];
  const float* an_b2 = (const float*)d_in[18];
  float* out = (float*)d_out;
  u16* hB   = (u16*)d_ws;
  u16* blob = hB + BLOB_U16;
  float* baseRcG = (float*)d_ws + BASE_RC_F32;
  float* baseAnG = (float*)d_ws + BASE_AN_F32;
  float* rc1pG   = (float*)d_ws + RC1P_F32;
  float* an1pG   = (float*)d_ws + AN1P_F32;
  const int has_pre   = (ws_size >= WS_NEED_PRE) ? 1 : 0;
  const int has_bases = (ws_size >= WS_NEED_BASES) ? 1 : 0;
  (void)n_in; (void)in_sizes;

  hipMemsetAsync(d_out, 0, (size_t)out_size * sizeof(float), stream);
  enc_prep_kernel<<<464, TPB, 0, stream>>>(s, se_w1, se_b1, se_w2, se_b2,
                                           sd_w1, sd_b1, sd_w2, sd_b2,
                                           rc_w1, rc_b1, rc_w2, rc_w3,
                                           an_w1, an_b1, an_w2,
                                           hB, blob, baseRcG, baseAnG, rc1pG, an1pG,
                                           has_bases, has_pre, out);
  pair_mfma_kernel<<<8192, TPB, 0, stream>>>(hB, blob, baseRcG, baseAnG, rc1pG, an1pG,
                                             has_bases, has_pre,
                                             rc_w1, rc_b1, rc_b2, rc_b3,
                                             an_w1, an_b1, an_b2, out);
}

// Round 9
// 203.286 us; speedup vs baseline: 1.0959x; 1.0959x over previous
//
#include <hip/hip_runtime.h>
#include <math.h>

#define TPB 256

typedef unsigned short u16;
typedef __attribute__((ext_vector_type(8))) short bf16x8;
typedef __attribute__((ext_vector_type(4))) float f32x4;

// ---------------- ws layout ----------------
// hB  : u16[524288]   @ u16 0        (1 MB)   h as RNE bf16 [b][n][64]
// blob: u16[106496]   @ u16 524288   (208 KB) fragment-linear A images
// baseRc : f32[1048576] @ f32 327680   (4 MB)  [b*64+i][128]
// baseAn : f32[524288]  @ f32 1376256  (2 MB)  [b*64+i][64]
// rc1_pre: f32[1048576] @ f32 1900544  (4 MB)  fragment order
// an1_pre: f32[524288]  @ f32 2949120  (2 MB)  fragment order
#define BLOB_U16 524288
#define BASE_RC_F32 327680
#define BASE_AN_F32 1376256
#define RC1P_F32 1900544
#define AN1P_F32 2949120
#define WS_NEED_BASES ((size_t)1900544 * 4)  // ~7.6 MB
#define WS_NEED_PRE   ((size_t)3473408 * 4)  // ~13.9 MB
// blob-internal u16 offsets (hi[OK] then lo[OK]; lo unused for hi-only layers)
#define RC1F 0       // O=128, K=64  (rc_w1 rows 64..127) T=8 OK=8192  [2-term, fallback only]
#define AN1F 16384   // O=64,  K=64  (an_w1 rows 64..127) T=4 OK=4096  [2-term, fallback only]
#define AN2F 24576   // O=128, K=64  T=8 OK=8192  [hi-only RNE]
#define RC2F 40960   // O=128, K=128 T=8 OK=16384 [hi-only RNE]
#define RC3F 73728   // O=128, K=128 T=8 OK=16384 [hi-only RNE]

__device__ __forceinline__ float b2f(u16 h) {
  return __uint_as_float(((unsigned)h) << 16);
}
__device__ __forceinline__ void split_bf16(float x, u16& hi, u16& lo) {
  unsigned u = __float_as_uint(x);
  hi = (u16)(u >> 16);
  float hif = __uint_as_float(u & 0xFFFF0000u);
  lo = (u16)(__float_as_uint(x - hif) >> 16);
}
__device__ __forceinline__ u16 f2bf_rne(float x) {
  unsigned u = __float_as_uint(x);
  return (u16)((u + 0x7FFFu + ((u >> 16) & 1u)) >> 16);
}
// fast pack: two f32 -> bf16x2 via round-half-up + byte-perm
__device__ __forceinline__ unsigned pack_bf16_hu(float v0, float v1) {
  unsigned a = __float_as_uint(v0) + 0x8000u;
  unsigned b = __float_as_uint(v1) + 0x8000u;
  return __builtin_amdgcn_perm(b, a, 0x07060302u);
}

__device__ __forceinline__ void cp_lds(float* dst, const float* src, int nfloats, int tid) {
  const float4* s4 = (const float4*)src;
  float4* d4 = (float4*)dst;
  const int n4 = nfloats >> 2;
  for (int i = tid; i < n4; i += TPB) d4[i] = s4[i];
}
__device__ __forceinline__ void ld4(float r[4], const float* p) {
  float4 v = *(const float4*)p;
  r[0] = v.x; r[1] = v.y; r[2] = v.z; r[3] = v.w;
}
__device__ __forceinline__ void ld2(float r[2], const float* p) {
  float2 v = *(const float2*)p;
  r[0] = v.x; r[1] = v.y;
}

// ---------------------------------------------------------------------------
// Kernel A (fused): blocks 0..255 = encoder: h -> hB, self_dyn -> out (atomic),
// bases (do_bases) and f32 L1 h_j-pre GEMMs in fragment order (do_pre).
// Blocks 256..463 = weight prep into blob.
// ---------------------------------------------------------------------------
__global__ __launch_bounds__(TPB, 3) void enc_prep_kernel(
    const float* __restrict__ s_in,
    const float* __restrict__ se_w1, const float* __restrict__ se_b1,
    const float* __restrict__ se_w2, const float* __restrict__ se_b2,
    const float* __restrict__ sd_w1, const float* __restrict__ sd_b1,
    const float* __restrict__ sd_w2, const float* __restrict__ sd_b2,
    const float* __restrict__ rc_w1, const float* __restrict__ rc_b1,
    const float* __restrict__ rc_w2, const float* __restrict__ rc_w3,
    const float* __restrict__ an_w1, const float* __restrict__ an_b1,
    const float* __restrict__ an_w2,
    u16* __restrict__ hB, u16* __restrict__ blob,
    float* __restrict__ baseRcG, float* __restrict__ baseAnG,
    float* __restrict__ rc1pG, float* __restrict__ an1pG,
    int do_bases, int do_pre,
    float* __restrict__ out) {
  if (blockIdx.x >= 256) {
    int idx = (int)(blockIdx.x - 256) * TPB + threadIdx.x;
    if (idx >= 53248) return;
    int r, base, OK, T; const float* W; int Wld, krow0, twoTerm;
    if (idx < 8192)       { r = idx;         base = RC1F; OK = 8192;  T = 8; W = rc_w1; Wld = 128; krow0 = 64; twoTerm = 1; }
    else if (idx < 12288) { r = idx - 8192;  base = AN1F; OK = 4096;  T = 4; W = an_w1; Wld = 64;  krow0 = 64; twoTerm = 1; }
    else if (idx < 20480) { r = idx - 12288; base = AN2F; OK = 8192;  T = 8; W = an_w2; Wld = 128; krow0 = 0;  twoTerm = 0; }
    else if (idx < 36864) { r = idx - 20480; base = RC2F; OK = 16384; T = 8; W = rc_w2; Wld = 128; krow0 = 0;  twoTerm = 0; }
    else                  { r = idx - 36864; base = RC3F; OK = 16384; T = 8; W = rc_w3; Wld = 128; krow0 = 0;  twoTerm = 0; }
    const int u = r & 7;
    const int lane = (r >> 3) & 63;
    const int ct = r >> 9;
    const int c = (T == 8) ? (ct >> 3) : (ct >> 2);
    const int tg = (T == 8) ? (ct & 7) : (ct & 3);
    const int o = tg * 16 + (lane & 15);
    const int k = c * 32 + (lane >> 4) * 8 + u;
    const float x = W[(krow0 + k) * Wld + o];
    if (twoTerm) {
      u16 hi, lo; split_bf16(x, hi, lo);
      blob[base + r] = hi;
      blob[base + OK + r] = lo;
    } else {
      blob[base + r] = f2bf_rne(x);
    }
    return;
  }

  // ---- encoder role
  __shared__ __align__(16) float sX[2048];
  __shared__ __align__(16) float sH1[2048];
  __shared__ __align__(16) float sT[4096];
  __shared__ __align__(16) float sW[4096];
  __shared__ float sb1[64], sb2[64], sdb1[128], sdb2[128], srb1[128], sab1[64];

  const int tid = threadIdx.x;
  const int lg = tid >> 5;
  const int og = tid & 31;
  const int b = blockIdx.x >> 1;
  const int half = blockIdx.x & 1;
  const int row0 = b * 64 + half * 32;
  const int n0 = lg * 4;

  cp_lds(sX, s_in + row0 * 64, 2048, tid);
  cp_lds(sW, se_w1, 4096, tid);
  if (tid < 64) { sb1[tid] = se_b1[tid]; sb2[tid] = se_b2[tid]; }
  else if (tid < 192) { const int o = tid - 64; sdb1[o] = sd_b1[o]; sdb2[o] = sd_b2[o]; }
  if (tid < 128) srb1[tid] = rc_b1[tid];
  else if (tid < 192) sab1[tid - 128] = an_b1[tid - 128];
  __syncthreads();

  float a2[4][2];
#pragma unroll
  for (int nn = 0; nn < 4; nn++) { a2[nn][0] = 0.f; a2[nn][1] = 0.f; }
  for (int kk = 0; kk < 64; kk += 4) {
    float xr[4][4], wr[4][2];
#pragma unroll
    for (int nn = 0; nn < 4; nn++) ld4(xr[nn], &sX[(n0 + nn) * 64 + kk]);
#pragma unroll
    for (int t = 0; t < 4; t++) ld2(wr[t], &sW[(kk + t) * 64 + og * 2]);
#pragma unroll
    for (int t = 0; t < 4; t++)
#pragma unroll
      for (int nn = 0; nn < 4; nn++) {
        a2[nn][0] = fmaf(xr[nn][t], wr[t][0], a2[nn][0]);
        a2[nn][1] = fmaf(xr[nn][t], wr[t][1], a2[nn][1]);
      }
  }
#pragma unroll
  for (int nn = 0; nn < 4; nn++) {
    float2 v;
    v.x = fmaxf(a2[nn][0] + sb1[og * 2 + 0], 0.f);
    v.y = fmaxf(a2[nn][1] + sb1[og * 2 + 1], 0.f);
    *(float2*)&sH1[(n0 + nn) * 64 + og * 2] = v;
  }
  __syncthreads();
  cp_lds(sW, se_w2, 4096, tid);
  __syncthreads();

#pragma unroll
  for (int nn = 0; nn < 4; nn++) { a2[nn][0] = 0.f; a2[nn][1] = 0.f; }
  for (int kk = 0; kk < 64; kk += 4) {
    float xr[4][4], wr[4][2];
#pragma unroll
    for (int nn = 0; nn < 4; nn++) ld4(xr[nn], &sH1[(n0 + nn) * 64 + kk]);
#pragma unroll
    for (int t = 0; t < 4; t++) ld2(wr[t], &sW[(kk + t) * 64 + og * 2]);
#pragma unroll
    for (int t = 0; t < 4; t++)
#pragma unroll
      for (int nn = 0; nn < 4; nn++) {
        a2[nn][0] = fmaf(xr[nn][t], wr[t][0], a2[nn][0]);
        a2[nn][1] = fmaf(xr[nn][t], wr[t][1], a2[nn][1]);
      }
  }
#pragma unroll
  for (int nn = 0; nn < 4; nn++) {
    float2 v;
    v.x = fmaxf(a2[nn][0] + sb2[og * 2 + 0], 0.f);
    v.y = fmaxf(a2[nn][1] + sb2[og * 2 + 1], 0.f);
    *(float2*)&sX[(n0 + nn) * 64 + og * 2] = v;
    const int off = (row0 + n0 + nn) * 64 + og * 2;
    *(ushort2*)&hB[off] = make_ushort2(f2bf_rne(v.x), f2bf_rne(v.y));
  }
  __syncthreads();

  float a4[4][4];
#pragma unroll
  for (int nn = 0; nn < 4; nn++)
#pragma unroll
    for (int oo = 0; oo < 4; oo++) a4[nn][oo] = 0.f;
  for (int c = 0; c < 2; c++) {
    cp_lds(sW, sd_w1 + c * 32 * 128, 4096, tid);
    __syncthreads();
    for (int kk = 0; kk < 32; kk += 4) {
      float xr[4][4], wr[4][4];
#pragma unroll
      for (int nn = 0; nn < 4; nn++) ld4(xr[nn], &sX[(n0 + nn) * 64 + c * 32 + kk]);
#pragma unroll
      for (int t = 0; t < 4; t++) ld4(wr[t], &sW[(kk + t) * 128 + og * 4]);
#pragma unroll
      for (int t = 0; t < 4; t++)
#pragma unroll
        for (int nn = 0; nn < 4; nn++)
#pragma unroll
          for (int oo = 0; oo < 4; oo++)
            a4[nn][oo] = fmaf(xr[nn][t], wr[t][oo], a4[nn][oo]);
    }
    __syncthreads();
  }
#pragma unroll
  for (int nn = 0; nn < 4; nn++) {
    float4 v;
    v.x = fmaxf(a4[nn][0] + sdb1[og * 4 + 0], 0.f);
    v.y = fmaxf(a4[nn][1] + sdb1[og * 4 + 1], 0.f);
    v.z = fmaxf(a4[nn][2] + sdb1[og * 4 + 2], 0.f);
    v.w = fmaxf(a4[nn][3] + sdb1[og * 4 + 3], 0.f);
    *(float4*)&sT[(n0 + nn) * 128 + og * 4] = v;
  }
  __syncthreads();

#pragma unroll
  for (int nn = 0; nn < 4; nn++)
#pragma unroll
    for (int oo = 0; oo < 4; oo++) a4[nn][oo] = 0.f;
  for (int c = 0; c < 4; c++) {
    cp_lds(sW, sd_w2 + c * 32 * 128, 4096, tid);
    __syncthreads();
    for (int kk = 0; kk < 32; kk += 4) {
      float xr[4][4], wr[4][4];
#pragma unroll
      for (int nn = 0; nn < 4; nn++) ld4(xr[nn], &sT[(n0 + nn) * 128 + c * 32 + kk]);
#pragma unroll
      for (int t = 0; t < 4; t++) ld4(wr[t], &sW[(kk + t) * 128 + og * 4]);
#pragma unroll
      for (int t = 0; t < 4; t++)
#pragma unroll
        for (int nn = 0; nn < 4; nn++)
#pragma unroll
          for (int oo = 0; oo < 4; oo++)
            a4[nn][oo] = fmaf(xr[nn][t], wr[t][oo], a4[nn][oo]);
    }
    __syncthreads();
  }
  float p[4];
#pragma unroll
  for (int oo = 0; oo < 4; oo++)
    p[oo] = a4[0][oo] + a4[1][oo] + a4[2][oo] + a4[3][oo] + 4.f * sdb2[og * 4 + oo];
  *(float4*)&sH1[lg * 128 + og * 4] = make_float4(p[0], p[1], p[2], p[3]);
  __syncthreads();
  if (tid < 128) {
    float ssum = 0.f;
#pragma unroll
    for (int g = 0; g < 8; g++) ssum += sH1[g * 128 + tid];
    atomicAdd(&out[b * 128 + tid], ssum * (1.0f / 64.0f));
  }

  if (do_bases) {
    // ---- baseRc = rc_b1 + h @ rc_w1[0:64]
#pragma unroll
    for (int nn = 0; nn < 4; nn++)
#pragma unroll
      for (int oo = 0; oo < 4; oo++) a4[nn][oo] = 0.f;
    for (int c = 0; c < 2; c++) {
      __syncthreads();
      cp_lds(sW, rc_w1 + c * 32 * 128, 4096, tid);
      __syncthreads();
      for (int kk = 0; kk < 32; kk += 4) {
        float xr[4][4], wr[4][4];
#pragma unroll
        for (int nn = 0; nn < 4; nn++) ld4(xr[nn], &sX[(n0 + nn) * 64 + c * 32 + kk]);
#pragma unroll
        for (int t = 0; t < 4; t++) ld4(wr[t], &sW[(kk + t) * 128 + og * 4]);
#pragma unroll
        for (int t = 0; t < 4; t++)
#pragma unroll
          for (int nn = 0; nn < 4; nn++)
#pragma unroll
            for (int oo = 0; oo < 4; oo++)
              a4[nn][oo] = fmaf(xr[nn][t], wr[t][oo], a4[nn][oo]);
      }
    }
#pragma unroll
    for (int nn = 0; nn < 4; nn++) {
      float4 v;
      v.x = a4[nn][0] + srb1[og * 4 + 0];
      v.y = a4[nn][1] + srb1[og * 4 + 1];
      v.z = a4[nn][2] + srb1[og * 4 + 2];
      v.w = a4[nn][3] + srb1[og * 4 + 3];
      *(float4*)&baseRcG[(size_t)(row0 + n0 + nn) * 128 + og * 4] = v;
    }
    __syncthreads();
    cp_lds(sW, an_w1, 4096, tid);
    __syncthreads();
#pragma unroll
    for (int nn = 0; nn < 4; nn++) { a2[nn][0] = 0.f; a2[nn][1] = 0.f; }
    for (int kk = 0; kk < 64; kk += 4) {
      float xr[4][4], wr[4][2];
#pragma unroll
      for (int nn = 0; nn < 4; nn++) ld4(xr[nn], &sX[(n0 + nn) * 64 + kk]);
#pragma unroll
      for (int t = 0; t < 4; t++) ld2(wr[t], &sW[(kk + t) * 64 + og * 2]);
#pragma unroll
      for (int t = 0; t < 4; t++)
#pragma unroll
        for (int nn = 0; nn < 4; nn++) {
          a2[nn][0] = fmaf(xr[nn][t], wr[t][0], a2[nn][0]);
          a2[nn][1] = fmaf(xr[nn][t], wr[t][1], a2[nn][1]);
        }
    }
#pragma unroll
    for (int nn = 0; nn < 4; nn++) {
      float2 v;
      v.x = a2[nn][0] + sab1[og * 2 + 0];
      v.y = a2[nn][1] + sab1[og * 2 + 1];
      *(float2*)&baseAnG[(size_t)(row0 + n0 + nn) * 64 + og * 2] = v;
    }
  }

  if (do_pre) {
    // ---- rc1_pre = h @ rc_w1[64:128]  (f32, fragment order)
#pragma unroll
    for (int nn = 0; nn < 4; nn++)
#pragma unroll
      for (int oo = 0; oo < 4; oo++) a4[nn][oo] = 0.f;
    for (int c = 0; c < 2; c++) {
      __syncthreads();
      cp_lds(sW, rc_w1 + (64 + c * 32) * 128, 4096, tid);
      __syncthreads();
      for (int kk = 0; kk < 32; kk += 4) {
        float xr[4][4], wr[4][4];
#pragma unroll
        for (int nn = 0; nn < 4; nn++) ld4(xr[nn], &sX[(n0 + nn) * 64 + c * 32 + kk]);
#pragma unroll
        for (int t = 0; t < 4; t++) ld4(wr[t], &sW[(kk + t) * 128 + og * 4]);
#pragma unroll
        for (int t = 0; t < 4; t++)
#pragma unroll
          for (int nn = 0; nn < 4; nn++)
#pragma unroll
            for (int oo = 0; oo < 4; oo++)
              a4[nn][oo] = fmaf(xr[nn][t], wr[t][oo], a4[nn][oo]);
      }
    }
#pragma unroll
    for (int nn = 0; nn < 4; nn++) {
      const int jl = half * 32 + n0 + nn;
      const int addr = ((b * 8 + (og >> 2)) * 4 + (jl >> 4)) * 256 +
                       ((og & 3) * 16 + (jl & 15)) * 4;
      *(float4*)&rc1pG[addr] = make_float4(a4[nn][0], a4[nn][1], a4[nn][2], a4[nn][3]);
    }
    // ---- an1_pre = h @ an_w1[64:128]
    __syncthreads();
    cp_lds(sW, an_w1 + 64 * 64, 4096, tid);
    __syncthreads();
#pragma unroll
    for (int nn = 0; nn < 4; nn++) { a2[nn][0] = 0.f; a2[nn][1] = 0.f; }
    for (int kk = 0; kk < 64; kk += 4) {
      float xr[4][4], wr[4][2];
#pragma unroll
      for (int nn = 0; nn < 4; nn++) ld4(xr[nn], &sX[(n0 + nn) * 64 + kk]);
#pragma unroll
      for (int t = 0; t < 4; t++) ld2(wr[t], &sW[(kk + t) * 64 + og * 2]);
#pragma unroll
      for (int t = 0; t < 4; t++)
#pragma unroll
        for (int nn = 0; nn < 4; nn++) {
          a2[nn][0] = fmaf(xr[nn][t], wr[t][0], a2[nn][0]);
          a2[nn][1] = fmaf(xr[nn][t], wr[t][1], a2[nn][1]);
        }
    }
#pragma unroll
    for (int nn = 0; nn < 4; nn++) {
      const int jl = half * 32 + n0 + nn;
      const int addr = ((b * 4 + (og >> 3)) * 4 + (jl >> 4)) * 256 +
                       (((og >> 1) & 3) * 16 + (jl & 15)) * 4 + (og & 1) * 2;
      *(float2*)&an1pG[addr] = make_float2(a2[nn][0], a2[nn][1]);
    }
  }
}

// ---------------------------------------------------------------------------
// MFMA layer helpers (A from global blob; B from XOR-swizzled LDS).
// ---------------------------------------------------------------------------
template<int MT, int NCHUNK, int RSG, int TILES>
__device__ __forceinline__ void run_layer1(f32x4 (&acc)[MT][4],
    const u16* __restrict__ blobL,
    const u16* __restrict__ sB, int tg0, int quad, int l15) {
  const int lane = quad * 16 + l15;
#pragma unroll
  for (int c = 0; c < NCHUNK; ++c) {
    bf16x8 Ah[MT];
#pragma unroll
    for (int t = 0; t < MT; ++t)
      Ah[t] = *(const bf16x8*)(blobL + ((c * TILES + tg0 + t) * 64 + lane) * 8);
    const int slot = (4 * c + quad) ^ (l15 & 7);
    bf16x8 Bh[4];
#pragma unroll
    for (int s = 0; s < 4; ++s)
      Bh[s] = *(const bf16x8*)&sB[(16 * s + l15) * (RSG * 8) + slot * 8];
#pragma unroll
    for (int t = 0; t < MT; ++t)
#pragma unroll
      for (int s = 0; s < 4; ++s)
        acc[t][s] = __builtin_amdgcn_mfma_f32_16x16x32_bf16(Ah[t], Bh[s], acc[t][s], 0, 0, 0);
  }
}

// relu -> half-up bf16 pack -> swizzled LDS store. Bias already in acc.
template<int MT, int RSG>
__device__ __forceinline__ void store_acts_pk(const f32x4 (&acc)[MT][4],
                                              u16* dst, int o0, int quad, int l15) {
#pragma unroll
  for (int t = 0; t < MT; ++t) {
    const int ob = o0 + 16 * t + quad * 4;
    const int slot = (ob >> 3) ^ (l15 & 7);
    const int e = ob & 7;
#pragma unroll
    for (int s = 0; s < 4; ++s) {
      const int j = 16 * s + l15;
      uint2 pk;
      pk.x = pack_bf16_hu(fmaxf(acc[t][s][0], 0.f), fmaxf(acc[t][s][1], 0.f));
      pk.y = pack_bf16_hu(fmaxf(acc[t][s][2], 0.f), fmaxf(acc[t][s][3], 0.f));
      *(uint2*)&dst[j * (RSG * 8) + slot * 8 + e] = pk;
    }
  }
}

// ---------------------------------------------------------------------------
// Kernel B (MFMA): one block per (b,i). ~28 KB LDS, 4 blocks/CU (VGPR cap 128:
// R8's 5 blocks/CU capped VGPRs at ~96 and spilled 165 MB to scratch — never
// again). Fast path (has_pre): L1 = coalesced pre-frag loads + epilogue.
// Tail order rc2 -> an2 -> rc3 keeps att live only across rc3.
// ---------------------------------------------------------------------------
__global__ __launch_bounds__(TPB, 4) void pair_mfma_kernel(
    const u16* __restrict__ hB, const u16* __restrict__ blob,
    const float* __restrict__ baseRcG, const float* __restrict__ baseAnG,
    const float* __restrict__ rc1pG, const float* __restrict__ an1pG,
    int has_bases, int has_pre,
    const float* __restrict__ rc_w1, const float* __restrict__ rc_b1,
    const float* __restrict__ rc_b2, const float* __restrict__ rc_b3,
    const float* __restrict__ an_w1, const float* __restrict__ an_b1,
    const float* __restrict__ an_b2,
    float* __restrict__ out) {
  __shared__ __align__(16) u16 sAct[64 * 128];  // 16 KB
  __shared__ __align__(16) u16 sAn[64 * 64];    // 8 KB
  __shared__ float sHi[64], sDist[64];
  __shared__ float sBaseRc[128], sBaseAn[64], sW1d[128], sAnd[64];
  __shared__ float sB2[128], sB3[128], sAb2[128], sRed[128];

  const int tid = threadIdx.x;
  const int w = tid >> 6, lane = tid & 63;
  const int quad = lane >> 4, l15 = lane & 15;
  const int b = blockIdx.x >> 6, i = blockIdx.x & 63;
  const int o0 = w * 32;
  const int o0a = w * 16;

  f32x4 accR[2][4];
  f32x4 accN[1][4];

  if (has_pre) {
    // ======== fast path: no h_j staging, no L1 MFMA ========
    if (tid < 128) {
      sW1d[tid] = rc_w1[128 * 128 + tid];
      sB2[tid] = rc_b2[tid]; sB3[tid] = rc_b3[tid]; sAb2[tid] = an_b2[tid];
    } else if (tid < 192) {
      sAnd[tid - 128] = an_w1[128 * 64 + (tid - 128)];
    } else {
      const int j = tid - 192;
      const float hi0 = b2f(hB[(b * 64 + i) * 64 + 0]);
      const float hi1 = b2f(hB[(b * 64 + i) * 64 + 1]);
      const ushort2 hj = *(const ushort2*)&hB[(b * 64 + j) * 64];
      const float d0 = hi0 - b2f(hj.x), d1 = hi1 - b2f(hj.y);
      sDist[j] = d0 * d0 + d1 * d1;
    }
    if (tid < 32)
      ((float4*)sBaseRc)[tid] = ((const float4*)(baseRcG + (size_t)(b * 64 + i) * 128))[tid];
    else if (tid < 48)
      ((float4*)sBaseAn)[tid - 32] = ((const float4*)(baseAnG + (size_t)(b * 64 + i) * 64))[tid - 32];
    __syncthreads();

    float bbR[2][4], wwR[2][4], bbN[4], wwN[4];
#pragma unroll
    for (int t = 0; t < 2; ++t) {
      ld4(bbR[t], &sBaseRc[o0 + 16 * t + quad * 4]);
      ld4(wwR[t], &sW1d[o0 + 16 * t + quad * 4]);
    }
    ld4(bbN, &sBaseAn[o0a + quad * 4]);
    ld4(wwN, &sAnd[o0a + quad * 4]);
    const float* pR = rc1pG + (size_t)(b * 8 + 2 * w) * 1024 + lane * 4;
    const float* pA = an1pG + (size_t)(b * 4 + w) * 1024 + lane * 4;
#pragma unroll
    for (int s = 0; s < 4; ++s) {
      const float dj = sDist[16 * s + l15];
#pragma unroll
      for (int t = 0; t < 2; ++t) {
        const float4 pre = *(const float4*)(pR + t * 1024 + s * 256);
        f32x4 a;
        a[0] = pre.x + fmaf(dj, wwR[t][0], bbR[t][0]);
        a[1] = pre.y + fmaf(dj, wwR[t][1], bbR[t][1]);
        a[2] = pre.z + fmaf(dj, wwR[t][2], bbR[t][2]);
        a[3] = pre.w + fmaf(dj, wwR[t][3], bbR[t][3]);
        accR[t][s] = a;
      }
      const float4 pre = *(const float4*)(pA + s * 256);
      f32x4 a;
      a[0] = pre.x + fmaf(dj, wwN[0], bbN[0]);
      a[1] = pre.y + fmaf(dj, wwN[1], bbN[1]);
      a[2] = pre.z + fmaf(dj, wwN[2], bbN[2]);
      a[3] = pre.w + fmaf(dj, wwN[3], bbN[3]);
      accN[0][s] = a;
    }
    store_acts_pk<1, 8>(accN, sAn, o0a, quad, l15);
    store_acts_pk<2, 16>(accR, sAct, o0, quad, l15);
    __syncthreads();
  } else {
    // ======== fallback: R7 path (L1 via MFMA, in-block/global bases) ========
    {
      const float4* srcJ = (const float4*)(hB + b * 4096);
      for (int idx = tid; idx < 512; idx += TPB) {
        const int row = idx >> 3, g = idx & 7;
        *(float4*)&sAct[row * 128 + ((g ^ (row & 7)) * 8)] = srcJ[idx];
      }
    }
    if (has_bases) {
      const float4* bR = (const float4*)(baseRcG + (size_t)(b * 64 + i) * 128);
      const float4* bA = (const float4*)(baseAnG + (size_t)(b * 64 + i) * 64);
      if (tid < 32) ((float4*)sBaseRc)[tid] = bR[tid];
      else if (tid < 48) ((float4*)sBaseAn)[tid - 32] = bA[tid - 32];
    }
    if (tid < 64) sHi[tid] = b2f(hB[(b * 64 + i) * 64 + tid]);
    if (tid < 128) {
      sW1d[tid] = rc_w1[128 * 128 + tid];
      sB2[tid] = rc_b2[tid]; sB3[tid] = rc_b3[tid]; sAb2[tid] = an_b2[tid];
    } else if (tid < 192) {
      sAnd[tid - 128] = an_w1[128 * 64 + (tid - 128)];
    }
    __syncthreads();
    if (!has_bases) {
      if (tid < 128) {
        float acc = rc_b1[tid];
        for (int k = 0; k < 64; ++k) acc = fmaf(sHi[k], rc_w1[k * 128 + tid], acc);
        sBaseRc[tid] = acc;
      } else if (tid < 192) {
        const int o = tid - 128;
        float acc = an_b1[o];
        for (int k = 0; k < 64; ++k) acc = fmaf(sHi[k], an_w1[k * 64 + o], acc);
        sBaseAn[o] = acc;
      }
    }
    if (tid >= 192) {
      const int j = tid - 192;
      const int base = j * 128 + ((0 ^ (j & 7)) * 8);
      const float d0 = sHi[0] - b2f(sAct[base + 0]);
      const float d1 = sHi[1] - b2f(sAct[base + 1]);
      sDist[j] = d0 * d0 + d1 * d1;
    }
    __syncthreads();

    {
      float bbR[2][4], wwR[2][4], bbN[4], wwN[4];
#pragma unroll
      for (int t = 0; t < 2; ++t) {
        ld4(bbR[t], &sBaseRc[o0 + 16 * t + quad * 4]);
        ld4(wwR[t], &sW1d[o0 + 16 * t + quad * 4]);
      }
      ld4(bbN, &sBaseAn[o0a + quad * 4]);
      ld4(wwN, &sAnd[o0a + quad * 4]);
#pragma unroll
      for (int s = 0; s < 4; ++s) {
        const float dj = sDist[16 * s + l15];
#pragma unroll
        for (int t = 0; t < 2; ++t) {
          f32x4 a;
#pragma unroll
          for (int r = 0; r < 4; ++r) a[r] = fmaf(dj, wwR[t][r], bbR[t][r]);
          accR[t][s] = a;
        }
        f32x4 a;
#pragma unroll
        for (int r = 0; r < 4; ++r) a[r] = fmaf(dj, wwN[r], bbN[r]);
        accN[0][s] = a;
      }
    }
    {
      const int lane64 = quad * 16 + l15;
#pragma unroll
      for (int c = 0; c < 2; ++c) {
        bf16x8 Ah[2], Al[2], AhN, AlN;
#pragma unroll
        for (int t = 0; t < 2; ++t) {
          const u16* p = blob + RC1F + ((c * 8 + 2 * w + t) * 64 + lane64) * 8;
          Ah[t] = *(const bf16x8*)p;
          Al[t] = *(const bf16x8*)(p + 8192);
        }
        {
          const u16* p = blob + AN1F + ((c * 4 + w) * 64 + lane64) * 8;
          AhN = *(const bf16x8*)p;
          AlN = *(const bf16x8*)(p + 4096);
        }
        const int slot = (4 * c + quad) ^ (l15 & 7);
        bf16x8 Bh[4];
#pragma unroll
        for (int s = 0; s < 4; ++s)
          Bh[s] = *(const bf16x8*)&sAct[(16 * s + l15) * 128 + slot * 8];
#pragma unroll
        for (int s = 0; s < 4; ++s) {
#pragma unroll
          for (int t = 0; t < 2; ++t) {
            f32x4 a = accR[t][s];
            a = __builtin_amdgcn_mfma_f32_16x16x32_bf16(Ah[t], Bh[s], a, 0, 0, 0);
            a = __builtin_amdgcn_mfma_f32_16x16x32_bf16(Al[t], Bh[s], a, 0, 0, 0);
            accR[t][s] = a;
          }
          f32x4 a = accN[0][s];
          a = __builtin_amdgcn_mfma_f32_16x16x32_bf16(AhN, Bh[s], a, 0, 0, 0);
          a = __builtin_amdgcn_mfma_f32_16x16x32_bf16(AlN, Bh[s], a, 0, 0, 0);
          accN[0][s] = a;
        }
      }
    }
    store_acts_pk<1, 8>(accN, sAn, o0a, quad, l15);
    __syncthreads();
    store_acts_pk<2, 16>(accR, sAct, o0, quad, l15);
    __syncthreads();
  }

  // ======== common tail (rc2 first so att is live only across rc3) ========
  // ---- rc-L2 (init = rc_b2), hi-only, write back in place
  {
    float bb[2][4];
#pragma unroll
    for (int t = 0; t < 2; ++t) ld4(bb[t], &sB2[o0 + 16 * t + quad * 4]);
#pragma unroll
    for (int t = 0; t < 2; ++t)
#pragma unroll
      for (int s = 0; s < 4; ++s) {
        f32x4 a;
#pragma unroll
        for (int r = 0; r < 4; ++r) a[r] = bb[t][r];
        accR[t][s] = a;
      }
  }
  run_layer1<2, 4, 16, 8>(accR, blob + RC2F, sAct, 2 * w, quad, l15);
  __syncthreads();
  store_acts_pk<2, 16>(accR, sAct, o0, quad, l15);
  __syncthreads();

  // ---- an-L2 -> att in regs (init = an_b2)
  f32x4 accT[2][4];
  {
    float bb[2][4];
#pragma unroll
    for (int t = 0; t < 2; ++t) ld4(bb[t], &sAb2[o0 + 16 * t + quad * 4]);
#pragma unroll
    for (int t = 0; t < 2; ++t)
#pragma unroll
      for (int s = 0; s < 4; ++s) {
        f32x4 a;
#pragma unroll
        for (int r = 0; r < 4; ++r) a[r] = bb[t][r];
        accT[t][s] = a;
      }
  }
  run_layer1<2, 2, 8, 8>(accT, blob + AN2F, sAn, 2 * w, quad, l15);
  float att[2][4][4];
#pragma unroll
  for (int t = 0; t < 2; ++t)
#pragma unroll
    for (int s = 0; s < 4; ++s)
#pragma unroll
      for (int r = 0; r < 4; ++r)
        att[t][s][r] = 1.0f / (1.0f + __expf(-accT[t][s][r]));

  // ---- rc-L3 (init = rc_b3), hi-only + rel*att + reduce over j
  {
    float bb[2][4];
#pragma unroll
    for (int t = 0; t < 2; ++t) ld4(bb[t], &sB3[o0 + 16 * t + quad * 4]);
#pragma unroll
    for (int t = 0; t < 2; ++t)
#pragma unroll
      for (int s = 0; s < 4; ++s) {
        f32x4 a;
#pragma unroll
        for (int r = 0; r < 4; ++r) a[r] = bb[t][r];
        accR[t][s] = a;
      }
  }
  run_layer1<2, 4, 16, 8>(accR, blob + RC3F, sAct, 2 * w, quad, l15);
  float ps[2][4] = {{0.f, 0.f, 0.f, 0.f}, {0.f, 0.f, 0.f, 0.f}};
#pragma unroll
  for (int t = 0; t < 2; ++t)
#pragma unroll
    for (int s = 0; s < 4; ++s)
#pragma unroll
      for (int r = 0; r < 4; ++r) {
        const float rel = fmaxf(accR[t][s][r], 0.f);
        ps[t][r] = fmaf(rel, att[t][s][r], ps[t][r]);
      }
#pragma unroll
  for (int t = 0; t < 2; ++t)
#pragma unroll
    for (int r = 0; r < 4; ++r) {
      float v = ps[t][r];
      v += __shfl_xor(v, 1, 64);
      v += __shfl_xor(v, 2, 64);
      v += __shfl_xor(v, 4, 64);
      v += __shfl_xor(v, 8, 64);
      ps[t][r] = v;
    }
  if (l15 == 0) {
#pragma unroll
    for (int t = 0; t < 2; ++t)
#pragma unroll
      for (int r = 0; r < 4; ++r)
        sRed[o0 + 16 * t + quad * 4 + r] = ps[t][r];
  }
  __syncthreads();
  if (tid < 128)
    atomicAdd(&out[b * 128 + tid], sRed[tid] * (1.0f / 4096.0f));
}

extern "C" void kernel_launch(void* const* d_in, const int* in_sizes, int n_in,
                              void* d_out, int out_size, void* d_ws, size_t ws_size,
                              hipStream_t stream) {
  const float* s     = (const float*)d_in[0];
  const float* se_w1 = (const float*)d_in[1];
  const float* se_b1 = (const float*)d_in[2];
  const float* se_w2 = (const float*)d_in[3];
  const float* se_b2 = (const float*)d_in[4];
  const float* sd_w1 = (const float*)d_in[5];
  const float* sd_b1 = (const float*)d_in[6];
  const float* sd_w2 = (const float*)d_in[7];
  const float* sd_b2 = (const float*)d_in[8];
  const float* rc_w1 = (const float*)d_in[9];
  const float* rc_b1 = (const float*)d_in[10];
  const float* rc_w2 = (const float*)d_in[11];
  const float* rc_b2 = (const float*)d_in[12];
  const float* rc_w3 = (const float*)d_in[13];
  const float* rc_b3 = (const float*)d_in[14];
  const float* an_w1 = (const float*)d_in[15];
  const float* an_b1 = (const float*)d_in[16];
  const float* an_w2 = (const float*)d_in[17];
  const float* an_b2 = (const float*)d_in[18];
  float* out = (float*)d_out;
  u16* hB   = (u16*)d_ws;
  u16* blob = hB + BLOB_U16;
  float* baseRcG = (float*)d_ws + BASE_RC_F32;
  float* baseAnG = (float*)d_ws + BASE_AN_F32;
  float* rc1pG   = (float*)d_ws + RC1P_F32;
  float* an1pG   = (float*)d_ws + AN1P_F32;
  const int has_pre   = (ws_size >= WS_NEED_PRE) ? 1 : 0;
  const int has_bases = (ws_size >= WS_NEED_BASES) ? 1 : 0;
  (void)n_in; (void)in_sizes;

  hipMemsetAsync(d_out, 0, (size_t)out_size * sizeof(float), stream);
  enc_prep_kernel<<<464, TPB, 0, stream>>>(s, se_w1, se_b1, se_w2, se_b2,
                                           sd_w1, sd_b1, sd_w2, sd_b2,
                                           rc_w1, rc_b1, rc_w2, rc_w3,
                                           an_w1, an_b1, an_w2,
                                           hB, blob, baseRcG, baseAnG, rc1pG, an1pG,
                                           has_bases, has_pre, out);
  pair_mfma_kernel<<<8192, TPB, 0, stream>>>(hB, blob, baseRcG, baseAnG, rc1pG, an1pG,
                                             has_bases, has_pre,
                                             rc_w1, rc_b1, rc_b2, rc_b3,
                                             an_w1, an_b1, an_b2, out);
}